// Round 4
// baseline (284.655 us; speedup 1.0000x reference)
//
#include <hip/hip_runtime.h>

#define NV 163842          // vertices
#define NC 128             // channels
#define KN 7               // neighbors (incl. self)
#define NWELT (NC * KN * NC)  // 114688 elements per W
#define BN_EPS 1e-5f
#define NBLK 1281          // ceil(NV/128)
#define RG 32              // reduce groups
#define RROWS 41           // ceil(NBLK/RG)

typedef __attribute__((ext_vector_type(4))) float f32x4;
typedef __attribute__((ext_vector_type(8))) short bf16x8;
typedef __attribute__((ext_vector_type(8))) unsigned short u16x8;

static __device__ __forceinline__ unsigned short f2bf(float f) {
    union { float f; unsigned int u; } v; v.f = f;
    unsigned int r = v.u + 0x7fffu + ((v.u >> 16) & 1u);
    return (unsigned short)(r >> 16);
}
static __device__ __forceinline__ float bf2f(unsigned short s) {
    union { unsigned int u; float f; } v; v.u = ((unsigned int)s) << 16;
    return v.f;
}
static __device__ __forceinline__ void gload_lds16(const void* g, void* l) {
    __builtin_amdgcn_global_load_lds((const __attribute__((address_space(1))) void*)g,
                                     (__attribute__((address_space(3))) void*)l, 16, 0, 0);
}

// ---- kernel 1: fp32 -> bf16 for x, W1, W2 ----
__global__ void cvt_kernel(const float* __restrict__ x, const float* __restrict__ w1,
                           const float* __restrict__ w2, unsigned short* __restrict__ xbf,
                           unsigned short* __restrict__ w1bf, unsigned short* __restrict__ w2bf)
{
    const int total4 = (NV * NC + 2 * NWELT) / 4;
    for (int i = blockIdx.x * blockDim.x + threadIdx.x; i < total4; i += gridDim.x * blockDim.x) {
        int e = i * 4;
        const float* src; unsigned short* dst;
        if (e < NV * NC)              { src = x  + e;                  dst = xbf  + e; }
        else if (e < NV * NC + NWELT) { src = w1 + (e - NV * NC);      dst = w1bf + (e - NV * NC); }
        else                          { src = w2 + (e - NV * NC - NWELT); dst = w2bf + (e - NV * NC - NWELT); }
        float4 v = *(const float4*)src;
        ushort4 o;
        o.x = f2bf(v.x); o.y = f2bf(v.y); o.z = f2bf(v.z); o.w = f2bf(v.w);
        *(ushort4*)dst = o;
    }
}

// ---- conv kernel: gathered bf16 GEMM, 128x128 tile, 14 K-chunks of 64 ----
// A: 4-slot LDS pipeline (prefetch depth 3) via global_load_lds, pre-swizzled source.
// B: register double-buffer loaded 1 chunk ahead from global (L2-resident, 224KB).
// Counted vmcnt at each barrier (never 0 in steady state).
__global__ __launch_bounds__(512, 4)
void conv_kernel(const unsigned short* __restrict__ xin,   // bf16 [NV][128]
                 const int* __restrict__ neigh,            // [NV*7]
                 const unsigned short* __restrict__ wbf,   // bf16 [128][896]
                 unsigned short* __restrict__ hout,        // bf16 [NV][128]
                 float* __restrict__ psum, float* __restrict__ psq)  // [NBLK][128]
{
    __shared__ __align__(16) char smem[65536];   // 4 A-slots x 16KB

    const int t    = threadIdx.x;
    const int row0 = blockIdx.x * 128;
    const int w    = t >> 6;
    const int lane = t & 63;
    const int lrow = lane & 15;
    const int lgrp = lane >> 4;
    const int wr   = w >> 2;         // 0..1 -> 64-row half
    const int wc   = w & 3;          // 0..3 -> 32-col quarter

    const int sl   = lane & 7;       // 16B slot within 128B row-chunk
    const int r3   = lane >> 3;      // row within 8-row group
    const int srcoff = (sl ^ r3) << 4;   // pre-swizzled source byte offset

    const int rA0 = w * 16 + r3;
    const int g0  = (row0 + rA0     < NV) ? (row0 + rA0)     : (NV - 1);
    const int g1  = (row0 + rA0 + 8 < NV) ? (row0 + rA0 + 8) : (NV - 1);

    int idx0[KN], idx1[KN];
    #pragma unroll
    for (int k = 0; k < KN; ++k) {
        idx0[k] = neigh[g0 * KN + k];
        idx1[k] = neigh[g1 * KN + k];
    }

    const char* xinb = (const char*)xin;
    // B fragment bases: row (wc*32 + nf*16 + lrow), elem (c*64 + ks*32 + lgrp*8)
    const unsigned short* bb0 = wbf + (size_t)(wc * 32 + lrow) * (KN * NC) + lgrp * 8;
    const unsigned short* bb1 = bb0 + (size_t)16 * (KN * NC);

    f32x4 acc[4][2];
    #pragma unroll
    for (int mf = 0; mf < 4; ++mf)
        #pragma unroll
        for (int nf = 0; nf < 2; ++nf)
            acc[mf][nf] = (f32x4){0.f, 0.f, 0.f, 0.f};

    bf16x8 breg[2][2][2];   // [chunk&1][ks][nf] — all indices constant after unroll

#define STAGE_A(c) do {                                                                \
        char* lA_ = smem + ((c) & 3) * 16384 + w * 2048;                               \
        gload_lds16(xinb + (size_t)idx0[(c) >> 1] * 256 + ((c) & 1) * 128 + srcoff, lA_);        \
        gload_lds16(xinb + (size_t)idx1[(c) >> 1] * 256 + ((c) & 1) * 128 + srcoff, lA_ + 1024); \
    } while (0)
#define LOADB(c) do {                                                  \
        breg[(c) & 1][0][0] = *(const bf16x8*)(bb0 + (c) * 64);        \
        breg[(c) & 1][0][1] = *(const bf16x8*)(bb1 + (c) * 64);        \
        breg[(c) & 1][1][0] = *(const bf16x8*)(bb0 + (c) * 64 + 32);   \
        breg[(c) & 1][1][1] = *(const bf16x8*)(bb1 + (c) * 64 + 32);   \
    } while (0)

    // prologue: queue = A0(2) A1(2) A2(2) B0(4); wait A0 -> vmcnt(8)
    STAGE_A(0); STAGE_A(1); STAGE_A(2); LOADB(0);
    asm volatile("s_waitcnt vmcnt(8)" ::: "memory");
    __builtin_amdgcn_sched_barrier(0);
    __builtin_amdgcn_s_barrier();
    __builtin_amdgcn_sched_barrier(0);

    #pragma unroll
    for (int c = 0; c < 14; ++c) {
        if (c < 13) LOADB(c + 1);
        if (c < 11) STAGE_A(c + 3);
        __builtin_amdgcn_sched_barrier(0);

        const char* Ab = smem + (c & 3) * 16384;
        __builtin_amdgcn_s_setprio(1);
        #pragma unroll
        for (int ks = 0; ks < 2; ++ks) {
            const int koff = ks * 64 + lgrp * 16;
            bf16x8 a[4];
            #pragma unroll
            for (int mf = 0; mf < 4; ++mf) {
                const int arow = wr * 64 + mf * 16 + lrow;
                a[mf] = *(const bf16x8*)(Ab + ((arow * 128 + koff) ^ ((arow & 7) << 4)));
            }
            #pragma unroll
            for (int mf = 0; mf < 4; ++mf) {
                acc[mf][0] = __builtin_amdgcn_mfma_f32_16x16x32_bf16(a[mf], breg[c & 1][ks][0], acc[mf][0], 0, 0, 0);
                acc[mf][1] = __builtin_amdgcn_mfma_f32_16x16x32_bf16(a[mf], breg[c & 1][ks][1], acc[mf][1], 0, 0, 0);
            }
        }
        __builtin_amdgcn_s_setprio(0);

        if (c < 13) {
            __builtin_amdgcn_sched_barrier(0);
            // counted wait: retire through A(c+1); loads younger than A(c+1):
            //   steady (c<=10): B(c)4 + A(c+2)2 + B(c+1)4 + A(c+3)2 = 12
            //   c==11: 10 ; c==12: 8
            if (c <= 10)      asm volatile("s_waitcnt vmcnt(12)" ::: "memory");
            else if (c == 11) asm volatile("s_waitcnt vmcnt(10)" ::: "memory");
            else              asm volatile("s_waitcnt vmcnt(8)"  ::: "memory");
            __builtin_amdgcn_sched_barrier(0);
            __builtin_amdgcn_s_barrier();
            __builtin_amdgcn_sched_barrier(0);
        }
    }
#undef STAGE_A
#undef LOADB

    // ---- epilogue: store bf16 h, block-reduce per-channel sum/sumsq (masked tail) ----
    // redsum/redsq live in slot 0 bytes [0,2048); last chunk reads slot 1 — no overlap.
    float* redsum = (float*)smem;            // [2][128]
    float* redsq  = (float*)(smem + 1024);   // [2][128]

    #pragma unroll
    for (int nf = 0; nf < 2; ++nf) {
        const int col = wc * 32 + nf * 16 + lrow;
        float sum = 0.f, sq = 0.f;
        #pragma unroll
        for (int mf = 0; mf < 4; ++mf) {
            const int rbase = row0 + wr * 64 + mf * 16 + lgrp * 4;
            #pragma unroll
            for (int r = 0; r < 4; ++r) {
                float v = acc[mf][nf][r];
                const int grow = rbase + r;
                if (grow < NV) {
                    sum += v; sq += v * v;
                    hout[(size_t)grow * NC + col] = f2bf(v);
                }
            }
        }
        sum += __shfl_xor(sum, 16); sum += __shfl_xor(sum, 32);
        sq  += __shfl_xor(sq, 16);  sq  += __shfl_xor(sq, 32);
        if (lgrp == 0) { redsum[wr * 128 + col] = sum; redsq[wr * 128 + col] = sq; }
    }
    __syncthreads();
    if (t < 128) {
        psum[(size_t)blockIdx.x * 128 + t] = redsum[t] + redsum[128 + t];
        psq[(size_t)blockIdx.x * 128 + t]  = redsq[t]  + redsq[128 + t];
    }
}

// ---- deterministic two-level stats reduction ----
__global__ void bn_reduce_kernel(const float* __restrict__ psum, const float* __restrict__ psq,
                                 float* __restrict__ psum2, float* __restrict__ psq2)
{
    const int c = threadIdx.x;   // 128
    const int g = blockIdx.x;    // RG
    const int b0 = g * RROWS;
    const int b1 = (b0 + RROWS < NBLK) ? b0 + RROWS : NBLK;
    float s = 0.f, q = 0.f;
    for (int b = b0; b < b1; ++b) {
        s += psum[b * 128 + c];
        q += psq[b * 128 + c];
    }
    psum2[g * 128 + c] = s;
    psq2[g * 128 + c]  = q;
}

__global__ void bn_finalize_kernel(const float* __restrict__ psum2, const float* __restrict__ psq2,
                                   const float* __restrict__ gamma, const float* __restrict__ beta,
                                   float* __restrict__ scale, float* __restrict__ shift)
{
    const int c = threadIdx.x;
    float s = 0.f, q = 0.f;
    #pragma unroll
    for (int g = 0; g < RG; ++g) { s += psum2[g * 128 + c]; q += psq2[g * 128 + c]; }
    const float inv  = 1.f / (float)NV;
    const float mean = s * inv;
    const float var  = q * inv - mean * mean;
    const float sc   = gamma[c] * rsqrtf(var + BN_EPS);
    scale[c] = sc;
    shift[c] = beta[c] - mean * sc;
}

// ---- apply BN1 + leaky, bf16 -> bf16 ----
__global__ void bn_apply_kernel(const unsigned short* __restrict__ h, const float* __restrict__ scale,
                                const float* __restrict__ shift, unsigned short* __restrict__ outbf)
{
    __shared__ float ssc[NC], ssh[NC];
    if (threadIdx.x < NC) { ssc[threadIdx.x] = scale[threadIdx.x]; ssh[threadIdx.x] = shift[threadIdx.x]; }
    __syncthreads();
    const int total8 = NV * NC / 8;
    for (int i = blockIdx.x * blockDim.x + threadIdx.x; i < total8; i += gridDim.x * blockDim.x) {
        const int e = i * 8;
        const int c0 = e & (NC - 1);
        u16x8 v = *(const u16x8*)(h + e);
        u16x8 o;
        #pragma unroll
        for (int j = 0; j < 8; ++j) {
            float a = bf2f(v[j]) * ssc[c0 + j] + ssh[c0 + j];
            a = a >= 0.f ? a : 0.2f * a;
            o[j] = f2bf(a);
        }
        *(u16x8*)(outbf + e) = o;
    }
}

// ---- final: out = leaky(bn2(h2_bf16) + residual); residual from bf16 x if use_bf ----
__global__ void final_kernel(const unsigned short* __restrict__ h, const float* __restrict__ x,
                             const unsigned short* __restrict__ xb, const int use_bf,
                             const float* __restrict__ scale, const float* __restrict__ shift,
                             float* __restrict__ out)
{
    __shared__ float ssc[NC], ssh[NC];
    if (threadIdx.x < NC) { ssc[threadIdx.x] = scale[threadIdx.x]; ssh[threadIdx.x] = shift[threadIdx.x]; }
    __syncthreads();
    const int total8 = NV * NC / 8;
    for (int i = blockIdx.x * blockDim.x + threadIdx.x; i < total8; i += gridDim.x * blockDim.x) {
        const int e = i * 8;
        const int c0 = e & (NC - 1);
        u16x8 v = *(const u16x8*)(h + e);
        float xv[8];
        if (use_bf) {
            u16x8 xvb = *(const u16x8*)(xb + e);
            #pragma unroll
            for (int j = 0; j < 8; ++j) xv[j] = bf2f(xvb[j]);
        } else {
            float4 x0 = *(const float4*)(x + e);
            float4 x1 = *(const float4*)(x + e + 4);
            xv[0]=x0.x; xv[1]=x0.y; xv[2]=x0.z; xv[3]=x0.w;
            xv[4]=x1.x; xv[5]=x1.y; xv[6]=x1.z; xv[7]=x1.w;
        }
        float ov[8];
        #pragma unroll
        for (int j = 0; j < 8; ++j) {
            float a = bf2f(v[j]) * ssc[c0 + j] + ssh[c0 + j] + xv[j];
            ov[j] = a >= 0.f ? a : 0.2f * a;
        }
        float4 o0 = {ov[0], ov[1], ov[2], ov[3]};
        float4 o1 = {ov[4], ov[5], ov[6], ov[7]};
        *(float4*)(out + e)     = o0;
        *(float4*)(out + e + 4) = o1;
    }
}

extern "C" void kernel_launch(void* const* d_in, const int* in_sizes, int n_in,
                              void* d_out, int out_size, void* d_ws, size_t ws_size,
                              hipStream_t stream)
{
    const float* x      = (const float*)d_in[0];
    const int*   neigh  = (const int*)d_in[1];
    const float* W1     = (const float*)d_in[2];
    // d_in[3] = b1 (cancels through BN)
    const float* gamma1 = (const float*)d_in[4];
    const float* beta1  = (const float*)d_in[5];
    const float* W2     = (const float*)d_in[6];
    // d_in[7] = b2 (cancels through BN)
    const float* gamma2 = (const float*)d_in[8];
    const float* beta2  = (const float*)d_in[9];

    // d_out (84MB fp32) doubles as two bf16 scratch halves until final_kernel.
    unsigned short* h1pre = (unsigned short*)d_out;                    // bf16 [NV][128]
    unsigned short* h1bn  = (unsigned short*)d_out + (size_t)NV * NC;  // bf16 [NV][128]
    float* out = (float*)d_out;

    char* ws = (char*)d_ws;
    size_t off = 0;
    unsigned short* xbf  = (unsigned short*)(ws + off); off += (size_t)NV * NC * 2;
    unsigned short* w1bf = (unsigned short*)(ws + off); off += NWELT * 2;
    unsigned short* w2bf = (unsigned short*)(ws + off); off += NWELT * 2;
    float* psum  = (float*)(ws + off); off += (size_t)NBLK * 128 * 4;
    float* psq   = (float*)(ws + off); off += (size_t)NBLK * 128 * 4;
    float* psum2 = (float*)(ws + off); off += RG * 128 * 4;
    float* psq2  = (float*)(ws + off); off += RG * 128 * 4;
    float* scale1 = (float*)(ws + off); off += 512;
    float* shift1 = (float*)(ws + off); off += 512;
    float* scale2 = (float*)(ws + off); off += 512;
    float* shift2 = (float*)(ws + off); off += 512;

    // If ws has room for a dedicated h2 buffer, keep xbf alive and use bf16 x
    // for the residual (saves 42MB of fp32 x re-read). Deterministic in ws_size.
    const size_t h2_bytes = (size_t)NV * NC * 2;
    unsigned short* h2pre;
    int use_bf;
    if (off + h2_bytes <= ws_size) { h2pre = (unsigned short*)(ws + off); use_bf = 1; }
    else                           { h2pre = xbf;                        use_bf = 0; }

    cvt_kernel<<<2048, 256, 0, stream>>>(x, W1, W2, xbf, w1bf, w2bf);
    conv_kernel<<<NBLK, 512, 0, stream>>>(xbf, neigh, w1bf, h1pre, psum, psq);
    bn_reduce_kernel<<<RG, 128, 0, stream>>>(psum, psq, psum2, psq2);
    bn_finalize_kernel<<<1, 128, 0, stream>>>(psum2, psq2, gamma1, beta1, scale1, shift1);
    bn_apply_kernel<<<2048, 256, 0, stream>>>(h1pre, scale1, shift1, h1bn);
    conv_kernel<<<NBLK, 512, 0, stream>>>(h1bn, neigh, w2bf, h2pre, psum, psq);
    bn_reduce_kernel<<<RG, 128, 0, stream>>>(psum, psq, psum2, psq2);
    bn_finalize_kernel<<<1, 128, 0, stream>>>(psum2, psq2, gamma2, beta2, scale2, shift2);
    final_kernel<<<2048, 256, 0, stream>>>(h2pre, x, xbf, use_bf, scale2, shift2, out);
}

// Round 5
// 262.996 us; speedup vs baseline: 1.0824x; 1.0824x over previous
//
#include <hip/hip_runtime.h>

#define NV 163842          // vertices
#define NC 128             // channels
#define KN 7               // neighbors (incl. self)
#define NWELT (NC * KN * NC)  // 114688 elements per W
#define BN_EPS 1e-5f
#define NBLK 1281          // ceil(NV/128)
#define RG 32              // reduce groups
#define RROWS 41           // ceil(NBLK/RG)

typedef __attribute__((ext_vector_type(4))) float f32x4;
typedef __attribute__((ext_vector_type(8))) short bf16x8;
typedef __attribute__((ext_vector_type(8))) unsigned short u16x8;

static __device__ __forceinline__ unsigned short f2bf(float f) {
    union { float f; unsigned int u; } v; v.f = f;
    unsigned int r = v.u + 0x7fffu + ((v.u >> 16) & 1u);
    return (unsigned short)(r >> 16);
}
static __device__ __forceinline__ float bf2f(unsigned short s) {
    union { unsigned int u; float f; } v; v.u = ((unsigned int)s) << 16;
    return v.f;
}
static __device__ __forceinline__ void gload_lds16(const void* g, void* l) {
    __builtin_amdgcn_global_load_lds((const __attribute__((address_space(1))) void*)g,
                                     (__attribute__((address_space(3))) void*)l, 16, 0, 0);
}

// ---- kernel 1: fp32 -> bf16 for x, W1, W2 ----
__global__ void cvt_kernel(const float* __restrict__ x, const float* __restrict__ w1,
                           const float* __restrict__ w2, unsigned short* __restrict__ xbf,
                           unsigned short* __restrict__ w1bf, unsigned short* __restrict__ w2bf)
{
    const int total4 = (NV * NC + 2 * NWELT) / 4;
    for (int i = blockIdx.x * blockDim.x + threadIdx.x; i < total4; i += gridDim.x * blockDim.x) {
        int e = i * 4;
        const float* src; unsigned short* dst;
        if (e < NV * NC)              { src = x  + e;                  dst = xbf  + e; }
        else if (e < NV * NC + NWELT) { src = w1 + (e - NV * NC);      dst = w1bf + (e - NV * NC); }
        else                          { src = w2 + (e - NV * NC - NWELT); dst = w2bf + (e - NV * NC - NWELT); }
        float4 v = *(const float4*)src;
        ushort4 o;
        o.x = f2bf(v.x); o.y = f2bf(v.y); o.z = f2bf(v.z); o.w = f2bf(v.w);
        *(ushort4*)dst = o;
    }
}

// ---- conv kernel: gathered bf16 GEMM, 128x128 tile, 28 K-chunks of 32 ----
// Round-3 skeleton (double-buffered LDS via global_load_lds, pre-swizzled gather
// source, one vmcnt(0)+barrier per chunk) resized to 32KB LDS -> 4 blocks/CU.
// LDS rows are 64B (4x16B slots); swizzle: slot ^= (row>>1)&3  (2 lanes/bank = free).
__global__ __launch_bounds__(512, 8)
void conv_kernel(const unsigned short* __restrict__ xin,   // bf16 [NV][128]
                 const int* __restrict__ neigh,            // [NV*7]
                 const unsigned short* __restrict__ wbf,   // bf16 [128][896]
                 unsigned short* __restrict__ hout,        // bf16 [NV][128]
                 float* __restrict__ psum, float* __restrict__ psq)  // [NBLK][128]
{
    // 2 slots x (A 8KB @0 + B 8KB @8192) = 32KB
    __shared__ __align__(16) char smem[32768];

    const int t    = threadIdx.x;
    const int row0 = blockIdx.x * 128;
    const int w    = t >> 6;
    const int lane = t & 63;
    const int lrow = lane & 15;
    const int lgrp = lane >> 4;
    const int wr   = w >> 2;         // 0..1 -> 64-row half
    const int wc   = w & 3;          // 0..3 -> 32-col quarter

    // staging: 4 threads per row, 128 rows; each lane one 16B slot of a 64B chunk
    const int srow = t >> 2;                     // row in tile [0,128)
    const int sl   = t & 3;                      // 16B slot [0,4)
    const int srcoff = ((sl ^ ((srow >> 1) & 3)) << 4);   // pre-swizzled source byte offset

    const int g = (row0 + srow < NV) ? (row0 + srow) : (NV - 1);
    int idx[KN];
    #pragma unroll
    for (int k = 0; k < KN; ++k) idx[k] = neigh[g * KN + k];

    const char* xinb = (const char*)xin;
    const char* bsrc = (const char*)wbf + (size_t)srow * 1792 + srcoff;   // W row = output col

    f32x4 acc[4][2];
    #pragma unroll
    for (int mf = 0; mf < 4; ++mf)
        #pragma unroll
        for (int nf = 0; nf < 2; ++nf)
            acc[mf][nf] = (f32x4){0.f, 0.f, 0.f, 0.f};

    // chunk c covers K elems [c*32, c*32+32): neighbor k_=c>>2, row quarter q_=c&3
#define STAGE(c) do {                                                               \
        const int k_ = (c) >> 2, q_ = (c) & 3, bs_ = ((c) & 1) * 16384;             \
        gload_lds16(xinb + (size_t)idx[k_] * 256 + q_ * 64 + srcoff,                \
                    smem + bs_ + w * 1024);                                         \
        gload_lds16(bsrc + k_ * 256 + q_ * 64,                                      \
                    smem + bs_ + 8192 + w * 1024);                                  \
    } while (0)

    STAGE(0);
    asm volatile("s_waitcnt vmcnt(0)" ::: "memory");
    __builtin_amdgcn_s_barrier();
    __builtin_amdgcn_sched_barrier(0);

    #pragma unroll
    for (int c = 0; c < 28; ++c) {
        if (c < 27) STAGE(c + 1);

        const char* Ab = smem + (c & 1) * 16384;
        const char* Bb = Ab + 8192;
        bf16x8 a[4], b[2];
        #pragma unroll
        for (int mf = 0; mf < 4; ++mf) {
            const int arow = wr * 64 + mf * 16 + lrow;
            a[mf] = *(const bf16x8*)(Ab + arow * 64 + ((lgrp ^ ((arow >> 1) & 3)) << 4));
        }
        #pragma unroll
        for (int nf = 0; nf < 2; ++nf) {
            const int bcol = wc * 32 + nf * 16 + lrow;
            b[nf] = *(const bf16x8*)(Bb + bcol * 64 + ((lgrp ^ ((bcol >> 1) & 3)) << 4));
        }
        #pragma unroll
        for (int mf = 0; mf < 4; ++mf) {
            acc[mf][0] = __builtin_amdgcn_mfma_f32_16x16x32_bf16(a[mf], b[0], acc[mf][0], 0, 0, 0);
            acc[mf][1] = __builtin_amdgcn_mfma_f32_16x16x32_bf16(a[mf], b[1], acc[mf][1], 0, 0, 0);
        }

        if (c < 27) {
            asm volatile("s_waitcnt vmcnt(0)" ::: "memory");
            __builtin_amdgcn_sched_barrier(0);
            __builtin_amdgcn_s_barrier();
            __builtin_amdgcn_sched_barrier(0);
        }
    }
#undef STAGE

    // ---- epilogue: store bf16 h, block-reduce per-channel sum/sumsq (masked tail) ----
    // redsum/redsq in slot0 A region [0,2048); last chunk (c=27) read slot 1 — disjoint.
    float* redsum = (float*)smem;            // [2][128]
    float* redsq  = (float*)(smem + 1024);   // [2][128]

    #pragma unroll
    for (int nf = 0; nf < 2; ++nf) {
        const int col = wc * 32 + nf * 16 + lrow;
        float sum = 0.f, sq = 0.f;
        #pragma unroll
        for (int mf = 0; mf < 4; ++mf) {
            const int rbase = row0 + wr * 64 + mf * 16 + lgrp * 4;
            #pragma unroll
            for (int r = 0; r < 4; ++r) {
                float v = acc[mf][nf][r];
                const int grow = rbase + r;
                if (grow < NV) {
                    sum += v; sq += v * v;
                    hout[(size_t)grow * NC + col] = f2bf(v);
                }
            }
        }
        sum += __shfl_xor(sum, 16); sum += __shfl_xor(sum, 32);
        sq  += __shfl_xor(sq, 16);  sq  += __shfl_xor(sq, 32);
        if (lgrp == 0) { redsum[wr * 128 + col] = sum; redsq[wr * 128 + col] = sq; }
    }
    __syncthreads();
    if (t < 128) {
        psum[(size_t)blockIdx.x * 128 + t] = redsum[t] + redsum[128 + t];
        psq[(size_t)blockIdx.x * 128 + t]  = redsq[t]  + redsq[128 + t];
    }
}

// ---- deterministic two-level stats reduction ----
__global__ void bn_reduce_kernel(const float* __restrict__ psum, const float* __restrict__ psq,
                                 float* __restrict__ psum2, float* __restrict__ psq2)
{
    const int c = threadIdx.x;   // 128
    const int g = blockIdx.x;    // RG
    const int b0 = g * RROWS;
    const int b1 = (b0 + RROWS < NBLK) ? b0 + RROWS : NBLK;
    float s = 0.f, q = 0.f;
    for (int b = b0; b < b1; ++b) {
        s += psum[b * 128 + c];
        q += psq[b * 128 + c];
    }
    psum2[g * 128 + c] = s;
    psq2[g * 128 + c]  = q;
}

__global__ void bn_finalize_kernel(const float* __restrict__ psum2, const float* __restrict__ psq2,
                                   const float* __restrict__ gamma, const float* __restrict__ beta,
                                   float* __restrict__ scale, float* __restrict__ shift)
{
    const int c = threadIdx.x;
    float s = 0.f, q = 0.f;
    #pragma unroll
    for (int g = 0; g < RG; ++g) { s += psum2[g * 128 + c]; q += psq2[g * 128 + c]; }
    const float inv  = 1.f / (float)NV;
    const float mean = s * inv;
    const float var  = q * inv - mean * mean;
    const float sc   = gamma[c] * rsqrtf(var + BN_EPS);
    scale[c] = sc;
    shift[c] = beta[c] - mean * sc;
}

// ---- apply BN1 + leaky, bf16 -> bf16 ----
__global__ void bn_apply_kernel(const unsigned short* __restrict__ h, const float* __restrict__ scale,
                                const float* __restrict__ shift, unsigned short* __restrict__ outbf)
{
    __shared__ float ssc[NC], ssh[NC];
    if (threadIdx.x < NC) { ssc[threadIdx.x] = scale[threadIdx.x]; ssh[threadIdx.x] = shift[threadIdx.x]; }
    __syncthreads();
    const int total8 = NV * NC / 8;
    for (int i = blockIdx.x * blockDim.x + threadIdx.x; i < total8; i += gridDim.x * blockDim.x) {
        const int e = i * 8;
        const int c0 = e & (NC - 1);
        u16x8 v = *(const u16x8*)(h + e);
        u16x8 o;
        #pragma unroll
        for (int j = 0; j < 8; ++j) {
            float a = bf2f(v[j]) * ssc[c0 + j] + ssh[c0 + j];
            a = a >= 0.f ? a : 0.2f * a;
            o[j] = f2bf(a);
        }
        *(u16x8*)(outbf + e) = o;
    }
}

// ---- final: out = leaky(bn2(h2_bf16) + residual); residual from bf16 x if use_bf ----
__global__ void final_kernel(const unsigned short* __restrict__ h, const float* __restrict__ x,
                             const unsigned short* __restrict__ xb, const int use_bf,
                             const float* __restrict__ scale, const float* __restrict__ shift,
                             float* __restrict__ out)
{
    __shared__ float ssc[NC], ssh[NC];
    if (threadIdx.x < NC) { ssc[threadIdx.x] = scale[threadIdx.x]; ssh[threadIdx.x] = shift[threadIdx.x]; }
    __syncthreads();
    const int total8 = NV * NC / 8;
    for (int i = blockIdx.x * blockDim.x + threadIdx.x; i < total8; i += gridDim.x * blockDim.x) {
        const int e = i * 8;
        const int c0 = e & (NC - 1);
        u16x8 v = *(const u16x8*)(h + e);
        float xv[8];
        if (use_bf) {
            u16x8 xvb = *(const u16x8*)(xb + e);
            #pragma unroll
            for (int j = 0; j < 8; ++j) xv[j] = bf2f(xvb[j]);
        } else {
            float4 x0 = *(const float4*)(x + e);
            float4 x1 = *(const float4*)(x + e + 4);
            xv[0]=x0.x; xv[1]=x0.y; xv[2]=x0.z; xv[3]=x0.w;
            xv[4]=x1.x; xv[5]=x1.y; xv[6]=x1.z; xv[7]=x1.w;
        }
        float ov[8];
        #pragma unroll
        for (int j = 0; j < 8; ++j) {
            float a = bf2f(v[j]) * ssc[c0 + j] + ssh[c0 + j] + xv[j];
            ov[j] = a >= 0.f ? a : 0.2f * a;
        }
        float4 o0 = {ov[0], ov[1], ov[2], ov[3]};
        float4 o1 = {ov[4], ov[5], ov[6], ov[7]};
        *(float4*)(out + e)     = o0;
        *(float4*)(out + e + 4) = o1;
    }
}

extern "C" void kernel_launch(void* const* d_in, const int* in_sizes, int n_in,
                              void* d_out, int out_size, void* d_ws, size_t ws_size,
                              hipStream_t stream)
{
    const float* x      = (const float*)d_in[0];
    const int*   neigh  = (const int*)d_in[1];
    const float* W1     = (const float*)d_in[2];
    // d_in[3] = b1 (cancels through BN)
    const float* gamma1 = (const float*)d_in[4];
    const float* beta1  = (const float*)d_in[5];
    const float* W2     = (const float*)d_in[6];
    // d_in[7] = b2 (cancels through BN)
    const float* gamma2 = (const float*)d_in[8];
    const float* beta2  = (const float*)d_in[9];

    // d_out (84MB fp32) doubles as two bf16 scratch halves until final_kernel.
    unsigned short* h1pre = (unsigned short*)d_out;                    // bf16 [NV][128]
    unsigned short* h1bn  = (unsigned short*)d_out + (size_t)NV * NC;  // bf16 [NV][128]
    float* out = (float*)d_out;

    char* ws = (char*)d_ws;
    size_t off = 0;
    unsigned short* xbf  = (unsigned short*)(ws + off); off += (size_t)NV * NC * 2;
    unsigned short* w1bf = (unsigned short*)(ws + off); off += NWELT * 2;
    unsigned short* w2bf = (unsigned short*)(ws + off); off += NWELT * 2;
    float* psum  = (float*)(ws + off); off += (size_t)NBLK * 128 * 4;
    float* psq   = (float*)(ws + off); off += (size_t)NBLK * 128 * 4;
    float* psum2 = (float*)(ws + off); off += RG * 128 * 4;
    float* psq2  = (float*)(ws + off); off += RG * 128 * 4;
    float* scale1 = (float*)(ws + off); off += 512;
    float* shift1 = (float*)(ws + off); off += 512;
    float* scale2 = (float*)(ws + off); off += 512;
    float* shift2 = (float*)(ws + off); off += 512;

    // If ws has room for a dedicated h2 buffer, keep xbf alive and use bf16 x
    // for the residual (saves 42MB of fp32 x re-read). Deterministic in ws_size.
    const size_t h2_bytes = (size_t)NV * NC * 2;
    unsigned short* h2pre;
    int use_bf;
    if (off + h2_bytes <= ws_size) { h2pre = (unsigned short*)(ws + off); use_bf = 1; }
    else                           { h2pre = xbf;                        use_bf = 0; }

    cvt_kernel<<<2048, 256, 0, stream>>>(x, W1, W2, xbf, w1bf, w2bf);
    conv_kernel<<<NBLK, 512, 0, stream>>>(xbf, neigh, w1bf, h1pre, psum, psq);
    bn_reduce_kernel<<<RG, 128, 0, stream>>>(psum, psq, psum2, psq2);
    bn_finalize_kernel<<<1, 128, 0, stream>>>(psum2, psq2, gamma1, beta1, scale1, shift1);
    bn_apply_kernel<<<2048, 256, 0, stream>>>(h1pre, scale1, shift1, h1bn);
    conv_kernel<<<NBLK, 512, 0, stream>>>(h1bn, neigh, w2bf, h2pre, psum, psq);
    bn_reduce_kernel<<<RG, 128, 0, stream>>>(psum, psq, psum2, psq2);
    bn_finalize_kernel<<<1, 128, 0, stream>>>(psum2, psq2, gamma2, beta2, scale2, shift2);
    final_kernel<<<2048, 256, 0, stream>>>(h2pre, x, xbf, use_bf, scale2, shift2, out);
}

// Round 6
// 208.988 us; speedup vs baseline: 1.3621x; 1.2584x over previous
//
#include <hip/hip_runtime.h>

#define NV 163842          // vertices
#define NC 128             // channels
#define KN 7               // neighbors (incl. self)
#define NWELT (NC * KN * NC)  // 114688 elements per W
#define BN_EPS 1e-5f
#define NBLK 1281          // ceil(NV/128)
#define RG 32              // reduce groups
#define RROWS 41           // ceil(NBLK/RG)

typedef __attribute__((ext_vector_type(4))) float f32x4;
typedef __attribute__((ext_vector_type(8))) short bf16x8;
typedef __attribute__((ext_vector_type(8))) unsigned short u16x8;

static __device__ __forceinline__ unsigned short f2bf(float f) {
    union { float f; unsigned int u; } v; v.f = f;
    unsigned int r = v.u + 0x7fffu + ((v.u >> 16) & 1u);
    return (unsigned short)(r >> 16);
}
static __device__ __forceinline__ float bf2f(unsigned short s) {
    union { unsigned int u; float f; } v; v.u = ((unsigned int)s) << 16;
    return v.f;
}
static __device__ __forceinline__ void gload_lds16(const void* g, void* l) {
    __builtin_amdgcn_global_load_lds((const __attribute__((address_space(1))) void*)g,
                                     (__attribute__((address_space(3))) void*)l, 16, 0, 0);
}

// ---- kernel 1: fp32 -> bf16 for x, W1, W2 ----
__global__ void cvt_kernel(const float* __restrict__ x, const float* __restrict__ w1,
                           const float* __restrict__ w2, unsigned short* __restrict__ xbf,
                           unsigned short* __restrict__ w1bf, unsigned short* __restrict__ w2bf)
{
    const int total4 = (NV * NC + 2 * NWELT) / 4;
    for (int i = blockIdx.x * blockDim.x + threadIdx.x; i < total4; i += gridDim.x * blockDim.x) {
        int e = i * 4;
        const float* src; unsigned short* dst;
        if (e < NV * NC)              { src = x  + e;                  dst = xbf  + e; }
        else if (e < NV * NC + NWELT) { src = w1 + (e - NV * NC);      dst = w1bf + (e - NV * NC); }
        else                          { src = w2 + (e - NV * NC - NWELT); dst = w2bf + (e - NV * NC - NWELT); }
        float4 v = *(const float4*)src;
        ushort4 o;
        o.x = f2bf(v.x); o.y = f2bf(v.y); o.z = f2bf(v.z); o.w = f2bf(v.w);
        *(ushort4*)dst = o;
    }
}

// ---- conv kernel: gathered bf16 GEMM, 128x128 tile, 14 K-chunks of 64 ----
// Round-3 skeleton (gload_lds staging, pre-swizzled source, vmcnt(0)+barrier per
// chunk, dbuf 64KB -> 2 blocks/CU) with 4 waves of 64x64 output each (4x4 acc):
// halves LDS read traffic per FLOP vs the 8-wave 64x32 geometry.
__global__ __launch_bounds__(256, 2)
void conv_kernel(const unsigned short* __restrict__ xin,   // bf16 [NV][128]
                 const int* __restrict__ neigh,            // [NV*7]
                 const unsigned short* __restrict__ wbf,   // bf16 [128][896]
                 unsigned short* __restrict__ hout,        // bf16 [NV][128]
                 float* __restrict__ psum, float* __restrict__ psq)  // [NBLK][128]
{
    // 2 buffers x (A 16KB + B 16KB) = 64KB
    __shared__ __align__(16) char smem[65536];

    const int t    = threadIdx.x;
    const int row0 = blockIdx.x * 128;
    const int w    = t >> 6;         // 0..3
    const int lane = t & 63;
    const int lrow = lane & 15;
    const int lgrp = lane >> 4;
    const int wr   = w >> 1;         // 0..1 -> 64-row half
    const int wc   = w & 1;          // 0..1 -> 64-col half

    // staging: wave w covers rows w*32..w*32+31; lane covers rows w*32+r3+8j (j=0..3),
    // 16B slot sl of each 128B row-chunk, source pre-swizzled so LDS dest is linear.
    const int sl   = lane & 7;
    const int r3   = lane >> 3;          // 0..7 == row&7
    const int srcoff = (sl ^ r3) << 4;

    int idx[4][KN];
    #pragma unroll
    for (int j = 0; j < 4; ++j) {
        const int rr = row0 + w * 32 + r3 + 8 * j;
        const int g  = (rr < NV) ? rr : (NV - 1);
        #pragma unroll
        for (int k = 0; k < KN; ++k) idx[j][k] = neigh[g * KN + k];
    }

    const char* xinb  = (const char*)xin;
    const char* bsrcb = (const char*)wbf + (size_t)(w * 32 + r3) * 1792 + srcoff;

    f32x4 acc[4][4];
    #pragma unroll
    for (int mt = 0; mt < 4; ++mt)
        #pragma unroll
        for (int nt = 0; nt < 4; ++nt)
            acc[mt][nt] = (f32x4){0.f, 0.f, 0.f, 0.f};

    // chunk c: neighbor k_=c>>1, 128B row-half h_=c&1
#define STAGE(c) do {                                                                  \
        const int k_ = (c) >> 1, h_ = (c) & 1;                                         \
        char* lA = smem + ((c) & 1) * 32768 + w * 4096;                                \
        char* lB = lA + 16384;                                                         \
        gload_lds16(xinb + (size_t)idx[0][k_] * 256 + h_ * 128 + srcoff, lA);          \
        gload_lds16(xinb + (size_t)idx[1][k_] * 256 + h_ * 128 + srcoff, lA + 1024);   \
        gload_lds16(xinb + (size_t)idx[2][k_] * 256 + h_ * 128 + srcoff, lA + 2048);   \
        gload_lds16(xinb + (size_t)idx[3][k_] * 256 + h_ * 128 + srcoff, lA + 3072);   \
        gload_lds16(bsrcb +         k_ * 256 + h_ * 128, lB);                          \
        gload_lds16(bsrcb + 14336 + k_ * 256 + h_ * 128, lB + 1024);                   \
        gload_lds16(bsrcb + 28672 + k_ * 256 + h_ * 128, lB + 2048);                   \
        gload_lds16(bsrcb + 43008 + k_ * 256 + h_ * 128, lB + 3072);                   \
    } while (0)

    STAGE(0);
    asm volatile("s_waitcnt vmcnt(0)" ::: "memory");
    __builtin_amdgcn_s_barrier();
    __builtin_amdgcn_sched_barrier(0);

    #pragma unroll
    for (int c = 0; c < 14; ++c) {
        if (c < 13) STAGE(c + 1);

        const char* Ab = smem + (c & 1) * 32768;
        const char* Bb = Ab + 16384;
        #pragma unroll
        for (int ks = 0; ks < 2; ++ks) {
            const int koff = ks * 64 + lgrp * 16;
            bf16x8 a[4], b[4];
            #pragma unroll
            for (int mt = 0; mt < 4; ++mt) {
                const int arow = wr * 64 + mt * 16 + lrow;
                a[mt] = *(const bf16x8*)(Ab + ((arow * 128 + koff) ^ ((arow & 7) << 4)));
            }
            #pragma unroll
            for (int nt = 0; nt < 4; ++nt) {
                const int bcol = wc * 64 + nt * 16 + lrow;
                b[nt] = *(const bf16x8*)(Bb + ((bcol * 128 + koff) ^ ((bcol & 7) << 4)));
            }
            #pragma unroll
            for (int mt = 0; mt < 4; ++mt)
                #pragma unroll
                for (int nt = 0; nt < 4; ++nt)
                    acc[mt][nt] = __builtin_amdgcn_mfma_f32_16x16x32_bf16(a[mt], b[nt], acc[mt][nt], 0, 0, 0);
        }

        if (c < 13) {
            asm volatile("s_waitcnt vmcnt(0)" ::: "memory");
            __builtin_amdgcn_sched_barrier(0);
            __builtin_amdgcn_s_barrier();
            __builtin_amdgcn_sched_barrier(0);
        }
    }
#undef STAGE

    // ---- epilogue: store bf16 h, block-reduce per-channel sum/sumsq (masked tail) ----
    // redsum/redsq live in buf0 [0,2048); last chunk (c=13) read buf1 — disjoint.
    float* redsum = (float*)smem;            // [2][128]
    float* redsq  = (float*)(smem + 1024);   // [2][128]

    #pragma unroll
    for (int nt = 0; nt < 4; ++nt) {
        const int col = wc * 64 + nt * 16 + lrow;
        float sum = 0.f, sq = 0.f;
        #pragma unroll
        for (int mt = 0; mt < 4; ++mt) {
            const int rbase = row0 + wr * 64 + mt * 16 + lgrp * 4;
            #pragma unroll
            for (int r = 0; r < 4; ++r) {
                float v = acc[mt][nt][r];
                const int grow = rbase + r;
                if (grow < NV) {
                    sum += v; sq += v * v;
                    hout[(size_t)grow * NC + col] = f2bf(v);
                }
            }
        }
        sum += __shfl_xor(sum, 16); sum += __shfl_xor(sum, 32);
        sq  += __shfl_xor(sq, 16);  sq  += __shfl_xor(sq, 32);
        if (lgrp == 0) { redsum[wr * 128 + col] = sum; redsq[wr * 128 + col] = sq; }
    }
    __syncthreads();
    if (t < 128) {
        psum[(size_t)blockIdx.x * 128 + t] = redsum[t] + redsum[128 + t];
        psq[(size_t)blockIdx.x * 128 + t]  = redsq[t]  + redsq[128 + t];
    }
}

// ---- deterministic two-level stats reduction ----
__global__ void bn_reduce_kernel(const float* __restrict__ psum, const float* __restrict__ psq,
                                 float* __restrict__ psum2, float* __restrict__ psq2)
{
    const int c = threadIdx.x;   // 128
    const int g = blockIdx.x;    // RG
    const int b0 = g * RROWS;
    const int b1 = (b0 + RROWS < NBLK) ? b0 + RROWS : NBLK;
    float s = 0.f, q = 0.f;
    for (int b = b0; b < b1; ++b) {
        s += psum[b * 128 + c];
        q += psq[b * 128 + c];
    }
    psum2[g * 128 + c] = s;
    psq2[g * 128 + c]  = q;
}

__global__ void bn_finalize_kernel(const float* __restrict__ psum2, const float* __restrict__ psq2,
                                   const float* __restrict__ gamma, const float* __restrict__ beta,
                                   float* __restrict__ scale, float* __restrict__ shift)
{
    const int c = threadIdx.x;
    float s = 0.f, q = 0.f;
    #pragma unroll
    for (int g = 0; g < RG; ++g) { s += psum2[g * 128 + c]; q += psq2[g * 128 + c]; }
    const float inv  = 1.f / (float)NV;
    const float mean = s * inv;
    const float var  = q * inv - mean * mean;
    const float sc   = gamma[c] * rsqrtf(var + BN_EPS);
    scale[c] = sc;
    shift[c] = beta[c] - mean * sc;
}

// ---- apply BN1 + leaky, bf16 -> bf16 ----
__global__ void bn_apply_kernel(const unsigned short* __restrict__ h, const float* __restrict__ scale,
                                const float* __restrict__ shift, unsigned short* __restrict__ outbf)
{
    __shared__ float ssc[NC], ssh[NC];
    if (threadIdx.x < NC) { ssc[threadIdx.x] = scale[threadIdx.x]; ssh[threadIdx.x] = shift[threadIdx.x]; }
    __syncthreads();
    const int total8 = NV * NC / 8;
    for (int i = blockIdx.x * blockDim.x + threadIdx.x; i < total8; i += gridDim.x * blockDim.x) {
        const int e = i * 8;
        const int c0 = e & (NC - 1);
        u16x8 v = *(const u16x8*)(h + e);
        u16x8 o;
        #pragma unroll
        for (int j = 0; j < 8; ++j) {
            float a = bf2f(v[j]) * ssc[c0 + j] + ssh[c0 + j];
            a = a >= 0.f ? a : 0.2f * a;
            o[j] = f2bf(a);
        }
        *(u16x8*)(outbf + e) = o;
    }
}

// ---- final: out = leaky(bn2(h2_bf16) + residual); residual from bf16 x if use_bf ----
__global__ void final_kernel(const unsigned short* __restrict__ h, const float* __restrict__ x,
                             const unsigned short* __restrict__ xb, const int use_bf,
                             const float* __restrict__ scale, const float* __restrict__ shift,
                             float* __restrict__ out)
{
    __shared__ float ssc[NC], ssh[NC];
    if (threadIdx.x < NC) { ssc[threadIdx.x] = scale[threadIdx.x]; ssh[threadIdx.x] = shift[threadIdx.x]; }
    __syncthreads();
    const int total8 = NV * NC / 8;
    for (int i = blockIdx.x * blockDim.x + threadIdx.x; i < total8; i += gridDim.x * blockDim.x) {
        const int e = i * 8;
        const int c0 = e & (NC - 1);
        u16x8 v = *(const u16x8*)(h + e);
        float xv[8];
        if (use_bf) {
            u16x8 xvb = *(const u16x8*)(xb + e);
            #pragma unroll
            for (int j = 0; j < 8; ++j) xv[j] = bf2f(xvb[j]);
        } else {
            float4 x0 = *(const float4*)(x + e);
            float4 x1 = *(const float4*)(x + e + 4);
            xv[0]=x0.x; xv[1]=x0.y; xv[2]=x0.z; xv[3]=x0.w;
            xv[4]=x1.x; xv[5]=x1.y; xv[6]=x1.z; xv[7]=x1.w;
        }
        float ov[8];
        #pragma unroll
        for (int j = 0; j < 8; ++j) {
            float a = bf2f(v[j]) * ssc[c0 + j] + ssh[c0 + j] + xv[j];
            ov[j] = a >= 0.f ? a : 0.2f * a;
        }
        float4 o0 = {ov[0], ov[1], ov[2], ov[3]};
        float4 o1 = {ov[4], ov[5], ov[6], ov[7]};
        *(float4*)(out + e)     = o0;
        *(float4*)(out + e + 4) = o1;
    }
}

extern "C" void kernel_launch(void* const* d_in, const int* in_sizes, int n_in,
                              void* d_out, int out_size, void* d_ws, size_t ws_size,
                              hipStream_t stream)
{
    const float* x      = (const float*)d_in[0];
    const int*   neigh  = (const int*)d_in[1];
    const float* W1     = (const float*)d_in[2];
    // d_in[3] = b1 (cancels through BN)
    const float* gamma1 = (const float*)d_in[4];
    const float* beta1  = (const float*)d_in[5];
    const float* W2     = (const float*)d_in[6];
    // d_in[7] = b2 (cancels through BN)
    const float* gamma2 = (const float*)d_in[8];
    const float* beta2  = (const float*)d_in[9];

    // d_out (84MB fp32) doubles as two bf16 scratch halves until final_kernel.
    unsigned short* h1pre = (unsigned short*)d_out;                    // bf16 [NV][128]
    unsigned short* h1bn  = (unsigned short*)d_out + (size_t)NV * NC;  // bf16 [NV][128]
    float* out = (float*)d_out;

    char* ws = (char*)d_ws;
    size_t off = 0;
    unsigned short* xbf  = (unsigned short*)(ws + off); off += (size_t)NV * NC * 2;
    unsigned short* w1bf = (unsigned short*)(ws + off); off += NWELT * 2;
    unsigned short* w2bf = (unsigned short*)(ws + off); off += NWELT * 2;
    float* psum  = (float*)(ws + off); off += (size_t)NBLK * 128 * 4;
    float* psq   = (float*)(ws + off); off += (size_t)NBLK * 128 * 4;
    float* psum2 = (float*)(ws + off); off += RG * 128 * 4;
    float* psq2  = (float*)(ws + off); off += RG * 128 * 4;
    float* scale1 = (float*)(ws + off); off += 512;
    float* shift1 = (float*)(ws + off); off += 512;
    float* scale2 = (float*)(ws + off); off += 512;
    float* shift2 = (float*)(ws + off); off += 512;

    // If ws has room for a dedicated h2 buffer, keep xbf alive and use bf16 x
    // for the residual (saves 42MB of fp32 x re-read). Deterministic in ws_size.
    const size_t h2_bytes = (size_t)NV * NC * 2;
    unsigned short* h2pre;
    int use_bf;
    if (off + h2_bytes <= ws_size) { h2pre = (unsigned short*)(ws + off); use_bf = 1; }
    else                           { h2pre = xbf;                        use_bf = 0; }

    cvt_kernel<<<2048, 256, 0, stream>>>(x, W1, W2, xbf, w1bf, w2bf);
    conv_kernel<<<NBLK, 256, 0, stream>>>(xbf, neigh, w1bf, h1pre, psum, psq);
    bn_reduce_kernel<<<RG, 128, 0, stream>>>(psum, psq, psum2, psq2);
    bn_finalize_kernel<<<1, 128, 0, stream>>>(psum2, psq2, gamma1, beta1, scale1, shift1);
    bn_apply_kernel<<<2048, 256, 0, stream>>>(h1pre, scale1, shift1, h1bn);
    conv_kernel<<<NBLK, 256, 0, stream>>>(h1bn, neigh, w2bf, h2pre, psum, psq);
    bn_reduce_kernel<<<RG, 128, 0, stream>>>(psum, psq, psum2, psq2);
    bn_finalize_kernel<<<1, 128, 0, stream>>>(psum2, psq2, gamma2, beta2, scale2, shift2);
    final_kernel<<<2048, 256, 0, stream>>>(h2pre, x, xbf, use_bf, scale2, shift2, out);
}